// Round 3
// baseline (19706.206 us; speedup 1.0000x reference)
//
#include <hip/hip_runtime.h>
#include <math.h>

#define H      1024
#define LBLP1  33        // LABEL_SIZE + 1
#define NE     4096
#define NS     4096
#define NSTEP  (NE - 1)  // 4095 scan steps
#define TGT    1
#define NWG    256
#define UPW    4         // hidden units per workgroup
#define ROWS   28        // 7 gates * UPW
#define SCAN_THREADS 512
#define SENTINEL 0xFFFFFFFFu

__device__ __forceinline__ float wave_sum(float v) {
#pragma unroll
    for (int o = 32; o > 0; o >>= 1) v += __shfl_xor(v, o, 64);
    return v;
}

__device__ __forceinline__ float softplusf(float x) {
    return x > 0.f ? x + log1pf(expf(-x)) : log1pf(expf(x));
}
__device__ __forceinline__ float sigmoidf(float x) {
    return 1.f / (1.f + expf(-x));
}

// EmbT[l*H + k] = Emb[k*LBLP1 + l]
__global__ void embT_kernel(const float* __restrict__ Emb, float* __restrict__ EmbT) {
    int l = blockIdx.x;
    for (int k = threadIdx.x; k < H; k += blockDim.x)
        EmbT[(size_t)l * H + k] = Emb[(size_t)k * LBLP1 + l];
}

// WEmb[row*33 + l] = dot(W[row,:], EmbT[l,:]) + d[row];  row = e*H + h
// One block per row; 4 waves cover the 33 labels.
__global__ void wemb_kernel(const float* __restrict__ W, const float* __restrict__ EmbT,
                            const float* __restrict__ dbias, float* __restrict__ WEmb) {
    int row  = blockIdx.x;
    int wave = threadIdx.x >> 6;
    int lane = threadIdx.x & 63;
    __shared__ float wrow[H];
    for (int i = threadIdx.x; i < H; i += blockDim.x) wrow[i] = W[(size_t)row * H + i];
    __syncthreads();
    float db = dbias[row];
    for (int l = wave; l < LBLP1; l += 4) {
        const float* ec = EmbT + (size_t)l * H;
        float a = 0.f;
#pragma unroll
        for (int m = 0; m < 16; ++m) {
            int k = lane + (m << 6);
            a = fmaf(wrow[k], ec[k], a);
        }
        a = wave_sum(a);
        if (lane == 0) WEmb[(size_t)row * LBLP1 + l] = a + db;
    }
}

// Persistent dataflow scan: 256 WGs, each owns 4 hidden units across all 7 gates.
// No barrier: producers write h via agent-scope write-through stores into all_h
// (pre-memset to SENTINEL); consumers poll their 16B slot until non-sentinel.
__global__ __launch_bounds__(SCAN_THREADS)
void scan_kernel(const float* __restrict__ WEmb, const float* __restrict__ U,
                 const int* __restrict__ label_seq, const float* __restrict__ time_seq,
                 float* __restrict__ all_h, float* __restrict__ all_o,
                 float* __restrict__ all_cb, float* __restrict__ all_cc,
                 float* __restrict__ all_dl) {
    const int tid  = threadIdx.x;
    const int wg   = blockIdx.x;
    const int wave = tid >> 6;
    const int lane = tid & 63;

    extern __shared__ float smem[];
    float* Uld    = smem;                 // ROWS * H
    float* h_sh   = Uld + ROWS * H;       // H (16B aligned: 28672*4 bytes offset)
    float* act_sh = h_sh + H;             // ROWS
    float* wes    = act_sh + 32;          // ROWS * LBLP1 (WEmb slice for this WG)

    // One-time staging: 28 rows of U (coalesced over k), WEmb slice.
    for (int idx = tid; idx < ROWS * H; idx += SCAN_THREADS) {
        int r = idx >> 10, k = idx & (H - 1);
        int e = r >> 2, j = r & 3;
        Uld[idx] = U[((size_t)e * H + (wg * UPW + j)) * H + k];
    }
    for (int idx = tid; idx < ROWS * LBLP1; idx += SCAN_THREADS) {
        int r = idx / LBLP1, l = idx - r * LBLP1;
        int e = r >> 2, j = r & 3;
        wes[idx] = WEmb[((size_t)e * H + (wg * UPW + j)) * LBLP1 + l];
    }

    float c_t = 0.f, cbar = 0.f;
    const float4* h4 = (const float4*)h_sh;

    for (int t = 0; t < NSTEP; ++t) {
        // uniform per-step scalars (L1/L2-resident, issued before the poll)
        const int   lab = label_seq[t];
        const float dt  = time_seq[t + 1] - time_seq[t];

        // --- acquire h_t: poll self-announcing data (t>0), zeros at t=0 ---
        if (tid < 256) {
            float4 hv;
            if (t > 0) {
                const unsigned* src = (const unsigned*)(all_h + (size_t)(t - 1) * H) + (tid << 2);
                unsigned v0, v1, v2, v3;
                do {
                    v0 = __hip_atomic_load(src + 0, __ATOMIC_RELAXED, __HIP_MEMORY_SCOPE_AGENT);
                    v1 = __hip_atomic_load(src + 1, __ATOMIC_RELAXED, __HIP_MEMORY_SCOPE_AGENT);
                    v2 = __hip_atomic_load(src + 2, __ATOMIC_RELAXED, __HIP_MEMORY_SCOPE_AGENT);
                    v3 = __hip_atomic_load(src + 3, __ATOMIC_RELAXED, __HIP_MEMORY_SCOPE_AGENT);
                } while (v0 == SENTINEL || v1 == SENTINEL || v2 == SENTINEL || v3 == SENTINEL);
                union { unsigned u[4]; float4 f; } cv;
                cv.u[0] = v0; cv.u[1] = v1; cv.u[2] = v2; cv.u[3] = v3;
                hv = cv.f;
            } else {
                hv = make_float4(0.f, 0.f, 0.f, 0.f);
            }
            ((float4*)h_sh)[tid] = hv;
        }
        __syncthreads();

        // --- 28 LDS float4 dots; h fragments hoisted across rows ---
        float4 hr[4];
#pragma unroll
        for (int m = 0; m < 4; ++m) hr[m] = h4[(m << 6) + lane];

#pragma unroll
        for (int i = 0; i < 4; ++i) {
            int r = wave + (i << 3);
            if (r < ROWS) {
                const float4* u4 = (const float4*)(Uld + (r << 10));
                float a = 0.f;
#pragma unroll
                for (int m = 0; m < 4; ++m) {
                    float4 u = u4[(m << 6) + lane];
                    a = fmaf(u.x, hr[m].x, a); a = fmaf(u.y, hr[m].y, a);
                    a = fmaf(u.z, hr[m].z, a); a = fmaf(u.w, hr[m].w, a);
                }
                a = wave_sum(a);
                if (lane == 0) {
                    float g = wes[r * LBLP1 + lab] + a;
                    int e = r >> 2;
                    float act;
                    if (e == 2)      act = tanhf(g);
                    else if (e == 6) act = softplusf(g);
                    else             act = sigmoidf(g);
                    act_sh[r] = act;
                }
            }
        }
        __syncthreads();

        // --- state update + h publication (4 threads of wave 0) ---
        if (tid < UPW) {
            float i_g = act_sh[tid],      f_g = act_sh[4 + tid];
            float z   = act_sh[8 + tid],  o   = act_sh[12 + tid];
            float i_b = act_sh[16 + tid], f_b = act_sh[20 + tid];
            float dl  = act_sh[24 + tid];
            float c   = fmaf(f_g, c_t, i_g * z);
            float cbn = fmaf(f_b, cbar, i_b * z);
            float ctn = cbn + (c - cbn) * expf(-dl * dt);
            float hn  = o * tanhf(ctn);
            c_t = ctn; cbar = cbn;
            size_t p = (size_t)t * H + wg * UPW + tid;
            __hip_atomic_store(&all_h[p], hn, __ATOMIC_RELAXED, __HIP_MEMORY_SCOPE_AGENT);
            all_o [p] = o;
            all_cb[p] = cbn;
            all_cc[p] = c;
            all_dl[p] = dl;
        }
        // no barrier: next iteration's poll provides all ordering we need;
        // h_sh rewrite at t+1 happens after this step's syncthreads pair.
    }
}

__global__ void term1_kernel(const float* __restrict__ all_h, const int* __restrict__ label_seq,
                             const float* __restrict__ w, const float* __restrict__ log_s,
                             const int* __restrict__ ignore_first, float* __restrict__ acc) {
    int beg = (*ignore_first) ? 1 : 0;
    int j = blockIdx.x;
    if (j >= (NSTEP - 1 - beg)) return;
    if (label_seq[1 + beg + j] != TGT) return;
    const float* hrow = all_h + (size_t)(beg + j) * H;
    const float* w0 = w + (TGT - 1) * H;
    float part = 0.f;
    for (int i = threadIdx.x; i < H; i += blockDim.x) part += hrow[i] * w0[i];
    __shared__ float red[4];
    part = wave_sum(part);
    if ((threadIdx.x & 63) == 0) red[threadIdx.x >> 6] = part;
    __syncthreads();
    if (threadIdx.x == 0) {
        float tot = red[0] + red[1] + red[2] + red[3];
        float s0 = expf(log_s[TGT - 1]);
        float lam = s0 * softplusf(tot / s0) + 1e-9f;
        atomicAdd(acc, logf(lam));
    }
}

__global__ void term2_kernel(const float* __restrict__ all_o, const float* __restrict__ all_cb,
                             const float* __restrict__ all_cc, const float* __restrict__ all_dl,
                             const int* __restrict__ sim_idx, const float* __restrict__ sim_time,
                             const float* __restrict__ time_seq, const float* __restrict__ w,
                             const float* __restrict__ log_s, float* __restrict__ acc) {
    int i = blockIdx.x;
    int idx = sim_idx[i];
    float dtp = sim_time[i] - time_seq[idx];
    size_t base = (size_t)idx * H;
    const float* w0 = w + (TGT - 1) * H;
    float part = 0.f;
    for (int hh = threadIdx.x; hh < H; hh += blockDim.x) {
        float cb = all_cb[base + hh];
        float cc = all_cc[base + hh];
        float dl = all_dl[base + hh];
        float oo = all_o [base + hh];
        float cs = cb + (cc - cb) * expf(-dl * dtp);
        part += oo * tanhf(cs) * w0[hh];
    }
    __shared__ float red[4];
    part = wave_sum(part);
    if ((threadIdx.x & 63) == 0) red[threadIdx.x >> 6] = part;
    __syncthreads();
    if (threadIdx.x == 0) {
        float tot = red[0] + red[1] + red[2] + red[3];
        float s0 = expf(log_s[TGT - 1]);
        float lam = s0 * softplusf(tot / s0) + 1e-9f;
        atomicAdd(acc + 1, lam);
    }
}

__global__ void finish_kernel(const float* __restrict__ acc, const float* __restrict__ time_seq,
                              float* __restrict__ out) {
    float T = time_seq[NE - 1] - time_seq[0];
    out[0] = -(acc[0] - acc[1] * (T / (float)NS));
}

extern "C" void kernel_launch(void* const* d_in, const int* in_sizes, int n_in,
                              void* d_out, int out_size, void* d_ws, size_t ws_size,
                              hipStream_t stream) {
    const int*   label_seq    = (const int*)  d_in[0];
    const float* time_seq     = (const float*)d_in[1];
    const float* sim_time     = (const float*)d_in[2];
    const int*   sim_idx      = (const int*)  d_in[3];
    const int*   ignore_first = (const int*)  d_in[4];
    const float* Emb   = (const float*)d_in[5];
    const float* W     = (const float*)d_in[6];
    const float* U     = (const float*)d_in[7];
    const float* dbias = (const float*)d_in[8];
    const float* w     = (const float*)d_in[9];
    const float* log_s = (const float*)d_in[10];
    float* out = (float*)d_out;

    float* ws = (float*)d_ws;
    size_t off = 0;
    float* acc    = ws + off;  off += 32;                    // [0]=term1, [1]=term2-sum
    float* EmbT   = ws + off;  off += (size_t)LBLP1 * H;
    float* WEmb   = ws + off;  off += 7 * H * LBLP1;
    off = (off + 3) & ~(size_t)3;                            // 16B align
    float* all_h  = ws + off;  off += (size_t)NSTEP * H;
    float* all_o  = ws + off;  off += (size_t)NSTEP * H;
    float* all_cb = ws + off;  off += (size_t)NSTEP * H;
    float* all_cc = ws + off;  off += (size_t)NSTEP * H;
    float* all_dl = ws + off;  off += (size_t)NSTEP * H;

    hipMemsetAsync(acc, 0, 2 * sizeof(float), stream);
    // sentinel-fill the h dataflow buffer (0xFFFFFFFF = -NaN, never produced)
    hipMemsetAsync(all_h, 0xFF, (size_t)NSTEP * H * sizeof(float), stream);

    hipLaunchKernelGGL(embT_kernel, dim3(LBLP1), dim3(256), 0, stream, Emb, EmbT);
    hipLaunchKernelGGL(wemb_kernel, dim3(7 * H), dim3(256), 0, stream,
                       W, EmbT, dbias, WEmb);

    unsigned int smem_bytes = (unsigned int)((ROWS * H + H + 32 + ROWS * LBLP1) * sizeof(float));
    hipFuncSetAttribute((const void*)scan_kernel, hipFuncAttributeMaxDynamicSharedMemorySize,
                        (int)smem_bytes);
    void* args[] = { (void*)&WEmb, (void*)&U, (void*)&label_seq, (void*)&time_seq,
                     (void*)&all_h, (void*)&all_o, (void*)&all_cb, (void*)&all_cc,
                     (void*)&all_dl };
    // cooperative launch only for the co-residency guarantee (no grid.sync inside)
    hipLaunchCooperativeKernel((void*)scan_kernel, dim3(NWG), dim3(SCAN_THREADS),
                               args, smem_bytes, stream);

    hipLaunchKernelGGL(term1_kernel, dim3(NSTEP - 1), dim3(256), 0, stream,
                       all_h, label_seq, w, log_s, ignore_first, acc);
    hipLaunchKernelGGL(term2_kernel, dim3(NS), dim3(256), 0, stream,
                       all_o, all_cb, all_cc, all_dl, sim_idx, sim_time, time_seq, w, log_s, acc);
    hipLaunchKernelGGL(finish_kernel, dim3(1), dim3(1), 0, stream, acc, time_seq, out);
}

// Round 4
// 19360.240 us; speedup vs baseline: 1.0179x; 1.0179x over previous
//
#include <hip/hip_runtime.h>
#include <math.h>

#define H      1024
#define LBLP1  33        // LABEL_SIZE + 1
#define NE     4096
#define NS     4096
#define NSTEP  (NE - 1)  // 4095 scan steps
#define TGT    1
#define NWG    256
#define UPW    4         // hidden units per workgroup
#define ROWS   28        // 7 gates * UPW
#define SCAN_THREADS 512
#define SENTINEL 0xFFFFFFFFu

__device__ __forceinline__ float wave_sum(float v) {
#pragma unroll
    for (int o = 32; o > 0; o >>= 1) v += __shfl_xor(v, o, 64);
    return v;
}

__device__ __forceinline__ float softplusf(float x) {
    return x > 0.f ? x + log1pf(expf(-x)) : log1pf(expf(x));
}
__device__ __forceinline__ float sigmoidf(float x) {
    return 1.f / (1.f + expf(-x));
}

// EmbT[l*H + k] = Emb[k*LBLP1 + l]
__global__ void embT_kernel(const float* __restrict__ Emb, float* __restrict__ EmbT) {
    int l = blockIdx.x;
    for (int k = threadIdx.x; k < H; k += blockDim.x)
        EmbT[(size_t)l * H + k] = Emb[(size_t)k * LBLP1 + l];
}

// WEmb[row*33 + l] = dot(W[row,:], EmbT[l,:]) + d[row];  row = e*H + h
__global__ void wemb_kernel(const float* __restrict__ W, const float* __restrict__ EmbT,
                            const float* __restrict__ dbias, float* __restrict__ WEmb) {
    int row  = blockIdx.x;
    int wave = threadIdx.x >> 6;
    int lane = threadIdx.x & 63;
    __shared__ float wrow[H];
    for (int i = threadIdx.x; i < H; i += blockDim.x) wrow[i] = W[(size_t)row * H + i];
    __syncthreads();
    float db = dbias[row];
    for (int l = wave; l < LBLP1; l += 4) {
        const float* ec = EmbT + (size_t)l * H;
        float a = 0.f;
#pragma unroll
        for (int m = 0; m < 16; ++m) {
            int k = lane + (m << 6);
            a = fmaf(wrow[k], ec[k], a);
        }
        a = wave_sum(a);
        if (lane == 0) WEmb[(size_t)row * LBLP1 + l] = a + db;
    }
}

// Persistent dataflow scan: 256 WGs, each owns 4 hidden units across all 7 gates.
// Self-announcing h (sentinel-filled all_h); ONE wave per WG polls the 4 KB
// (64 lanes x 64 B) and redistributes via LDS -> 4x fewer readers per line.
__global__ __launch_bounds__(SCAN_THREADS)
void scan_kernel(const float* __restrict__ WEmb, const float* __restrict__ U,
                 const int* __restrict__ label_seq, const float* __restrict__ time_seq,
                 float* __restrict__ all_h, float* __restrict__ all_o,
                 float* __restrict__ all_cb, float* __restrict__ all_cc,
                 float* __restrict__ all_dl) {
    const int tid  = threadIdx.x;
    const int wg   = blockIdx.x;
    const int wave = tid >> 6;
    const int lane = tid & 63;

    extern __shared__ float smem[];
    float* Uld    = smem;                 // ROWS * H      (16B-aligned)
    float* h_sh   = Uld + ROWS * H;       // H             (16B-aligned)
    float* act_sh = h_sh + H;             // 32
    float* wes    = act_sh + 32;          // ROWS * LBLP1

    // One-time staging: 28 rows of U (coalesced over k) + WEmb slice.
    for (int idx = tid; idx < ROWS * H; idx += SCAN_THREADS) {
        int r = idx >> 10, k = idx & (H - 1);
        int e = r >> 2, j = r & 3;
        Uld[idx] = U[((size_t)e * H + (wg * UPW + j)) * H + k];
    }
    for (int idx = tid; idx < ROWS * LBLP1; idx += SCAN_THREADS) {
        int r = idx / LBLP1, l = idx - r * LBLP1;
        int e = r >> 2, j = r & 3;
        wes[idx] = WEmb[((size_t)e * H + (wg * UPW + j)) * LBLP1 + l];
    }
    __syncthreads();   // staging complete (lets gb[] read wes before sync_a)

    float c_t = 0.f, cbar = 0.f;
    const float4* h4 = (const float4*)h_sh;

    for (int t = 0; t < NSTEP; ++t) {
        // uniform per-step scalars + gate biases (off the critical poll path)
        const int   lab = label_seq[t];
        const float dt  = time_seq[t + 1] - time_seq[t];
        float gb[4];
#pragma unroll
        for (int i = 0; i < 4; ++i) {
            int r = wave + (i << 3);
            gb[i] = (r < ROWS) ? wes[r * LBLP1 + lab] : 0.f;
        }

        // --- wave 0: acquire h_t (poll own 64B slice), redistribute via LDS ---
        if (wave == 0) {
            union { unsigned u[16]; float4 f[4]; } cv;
            if (t > 0) {
                const unsigned* src =
                    (const unsigned*)(all_h + (size_t)(t - 1) * H) + (lane << 4);
                for (;;) {
                    bool ok = true;
#pragma unroll
                    for (int j = 0; j < 16; ++j)
                        cv.u[j] = __hip_atomic_load(src + j, __ATOMIC_RELAXED,
                                                    __HIP_MEMORY_SCOPE_AGENT);
#pragma unroll
                    for (int j = 0; j < 16; ++j) ok &= (cv.u[j] != SENTINEL);
                    if (ok) break;
                }
            } else {
#pragma unroll
                for (int j = 0; j < 4; ++j) cv.f[j] = make_float4(0.f, 0.f, 0.f, 0.f);
            }
            float4* dst = (float4*)h_sh + (lane << 2);
#pragma unroll
            for (int j = 0; j < 4; ++j) dst[j] = cv.f[j];
        }
        __syncthreads();   // sync_a: h_sh ready

        // --- 28 LDS float4 dots; h fragments hoisted across rows ---
        float4 hr[4];
#pragma unroll
        for (int m = 0; m < 4; ++m) hr[m] = h4[(m << 6) + lane];

#pragma unroll
        for (int i = 0; i < 4; ++i) {
            int r = wave + (i << 3);
            if (r < ROWS) {
                const float4* u4 = (const float4*)(Uld + (r << 10));
                float a = 0.f;
#pragma unroll
                for (int m = 0; m < 4; ++m) {
                    float4 u = u4[(m << 6) + lane];
                    a = fmaf(u.x, hr[m].x, a); a = fmaf(u.y, hr[m].y, a);
                    a = fmaf(u.z, hr[m].z, a); a = fmaf(u.w, hr[m].w, a);
                }
                a = wave_sum(a);
                if (lane == 0) {
                    float g = gb[i] + a;
                    int e = r >> 2;
                    float act;
                    if (e == 2)      act = tanhf(g);
                    else if (e == 6) act = softplusf(g);
                    else             act = sigmoidf(g);
                    act_sh[r] = act;
                }
            }
        }
        __syncthreads();   // sync_b: act_sh ready

        // --- state update + h publication (4 threads of wave 0) ---
        if (tid < UPW) {
            float i_g = act_sh[tid],      f_g = act_sh[4 + tid];
            float z   = act_sh[8 + tid],  o   = act_sh[12 + tid];
            float i_b = act_sh[16 + tid], f_b = act_sh[20 + tid];
            float dl  = act_sh[24 + tid];
            float c   = fmaf(f_g, c_t, i_g * z);
            float cbn = fmaf(f_b, cbar, i_b * z);
            float ctn = cbn + (c - cbn) * expf(-dl * dt);
            float hn  = o * tanhf(ctn);
            c_t = ctn; cbar = cbn;
            size_t p = (size_t)t * H + wg * UPW + tid;
            __hip_atomic_store(&all_h[p], hn, __ATOMIC_RELAXED, __HIP_MEMORY_SCOPE_AGENT);
            all_o [p] = o;
            all_cb[p] = cbn;
            all_cc[p] = c;
            all_dl[p] = dl;
        }
        // no global barrier: the step-(t+1) poll provides all cross-WG ordering;
        // h_sh/act_sh rewrite hazards are covered by sync_a/sync_b above.
    }
}

__global__ void term1_kernel(const float* __restrict__ all_h, const int* __restrict__ label_seq,
                             const float* __restrict__ w, const float* __restrict__ log_s,
                             const int* __restrict__ ignore_first, float* __restrict__ acc) {
    int beg = (*ignore_first) ? 1 : 0;
    int j = blockIdx.x;
    if (j >= (NSTEP - 1 - beg)) return;
    if (label_seq[1 + beg + j] != TGT) return;
    const float* hrow = all_h + (size_t)(beg + j) * H;
    const float* w0 = w + (TGT - 1) * H;
    float part = 0.f;
    for (int i = threadIdx.x; i < H; i += blockDim.x) part += hrow[i] * w0[i];
    __shared__ float red[4];
    part = wave_sum(part);
    if ((threadIdx.x & 63) == 0) red[threadIdx.x >> 6] = part;
    __syncthreads();
    if (threadIdx.x == 0) {
        float tot = red[0] + red[1] + red[2] + red[3];
        float s0 = expf(log_s[TGT - 1]);
        float lam = s0 * softplusf(tot / s0) + 1e-9f;
        atomicAdd(acc, logf(lam));
    }
}

__global__ void term2_kernel(const float* __restrict__ all_o, const float* __restrict__ all_cb,
                             const float* __restrict__ all_cc, const float* __restrict__ all_dl,
                             const int* __restrict__ sim_idx, const float* __restrict__ sim_time,
                             const float* __restrict__ time_seq, const float* __restrict__ w,
                             const float* __restrict__ log_s, float* __restrict__ acc) {
    int i = blockIdx.x;
    int idx = sim_idx[i];
    float dtp = sim_time[i] - time_seq[idx];
    size_t base = (size_t)idx * H;
    const float* w0 = w + (TGT - 1) * H;
    float part = 0.f;
    for (int hh = threadIdx.x; hh < H; hh += blockDim.x) {
        float cb = all_cb[base + hh];
        float cc = all_cc[base + hh];
        float dl = all_dl[base + hh];
        float oo = all_o [base + hh];
        float cs = cb + (cc - cb) * expf(-dl * dtp);
        part += oo * tanhf(cs) * w0[hh];
    }
    __shared__ float red[4];
    part = wave_sum(part);
    if ((threadIdx.x & 63) == 0) red[threadIdx.x >> 6] = part;
    __syncthreads();
    if (threadIdx.x == 0) {
        float tot = red[0] + red[1] + red[2] + red[3];
        float s0 = expf(log_s[TGT - 1]);
        float lam = s0 * softplusf(tot / s0) + 1e-9f;
        atomicAdd(acc + 1, lam);
    }
}

__global__ void finish_kernel(const float* __restrict__ acc, const float* __restrict__ time_seq,
                              float* __restrict__ out) {
    float T = time_seq[NE - 1] - time_seq[0];
    out[0] = -(acc[0] - acc[1] * (T / (float)NS));
}

extern "C" void kernel_launch(void* const* d_in, const int* in_sizes, int n_in,
                              void* d_out, int out_size, void* d_ws, size_t ws_size,
                              hipStream_t stream) {
    const int*   label_seq    = (const int*)  d_in[0];
    const float* time_seq     = (const float*)d_in[1];
    const float* sim_time     = (const float*)d_in[2];
    const int*   sim_idx      = (const int*)  d_in[3];
    const int*   ignore_first = (const int*)  d_in[4];
    const float* Emb   = (const float*)d_in[5];
    const float* W     = (const float*)d_in[6];
    const float* U     = (const float*)d_in[7];
    const float* dbias = (const float*)d_in[8];
    const float* w     = (const float*)d_in[9];
    const float* log_s = (const float*)d_in[10];
    float* out = (float*)d_out;

    float* ws = (float*)d_ws;
    size_t off = 0;
    float* acc    = ws + off;  off += 32;                    // [0]=term1, [1]=term2-sum
    float* EmbT   = ws + off;  off += (size_t)LBLP1 * H;
    float* WEmb   = ws + off;  off += 7 * H * LBLP1;
    off = (off + 3) & ~(size_t)3;                            // 16B align
    float* all_h  = ws + off;  off += (size_t)NSTEP * H;
    float* all_o  = ws + off;  off += (size_t)NSTEP * H;
    float* all_cb = ws + off;  off += (size_t)NSTEP * H;
    float* all_cc = ws + off;  off += (size_t)NSTEP * H;
    float* all_dl = ws + off;  off += (size_t)NSTEP * H;

    hipMemsetAsync(acc, 0, 2 * sizeof(float), stream);
    // sentinel-fill the h dataflow buffer (0xFFFFFFFF = -NaN, never produced)
    hipMemsetAsync(all_h, 0xFF, (size_t)NSTEP * H * sizeof(float), stream);

    hipLaunchKernelGGL(embT_kernel, dim3(LBLP1), dim3(256), 0, stream, Emb, EmbT);
    hipLaunchKernelGGL(wemb_kernel, dim3(7 * H), dim3(256), 0, stream,
                       W, EmbT, dbias, WEmb);

    unsigned int smem_bytes = (unsigned int)((ROWS * H + H + 32 + ROWS * LBLP1) * sizeof(float));
    hipFuncSetAttribute((const void*)scan_kernel, hipFuncAttributeMaxDynamicSharedMemorySize,
                        (int)smem_bytes);
    void* args[] = { (void*)&WEmb, (void*)&U, (void*)&label_seq, (void*)&time_seq,
                     (void*)&all_h, (void*)&all_o, (void*)&all_cb, (void*)&all_cc,
                     (void*)&all_dl };
    // cooperative launch only for the co-residency guarantee (no grid.sync inside)
    hipLaunchCooperativeKernel((void*)scan_kernel, dim3(NWG), dim3(SCAN_THREADS),
                               args, smem_bytes, stream);

    hipLaunchKernelGGL(term1_kernel, dim3(NSTEP - 1), dim3(256), 0, stream,
                       all_h, label_seq, w, log_s, ignore_first, acc);
    hipLaunchKernelGGL(term2_kernel, dim3(NS), dim3(256), 0, stream,
                       all_o, all_cb, all_cc, all_dl, sim_idx, sim_time, time_seq, w, log_s, acc);
    hipLaunchKernelGGL(finish_kernel, dim3(1), dim3(1), 0, stream, acc, time_seq, out);
}

// Round 5
// 16361.459 us; speedup vs baseline: 1.2044x; 1.1833x over previous
//
#include <hip/hip_runtime.h>
#include <math.h>

#define H      1024
#define LBLP1  33        // LABEL_SIZE + 1
#define NE     4096
#define NS     4096
#define NSTEP  (NE - 1)  // 4095 scan steps
#define TGT    1
#define NWG    256
#define UPW    4         // hidden units per workgroup
#define ROWS   28        // 7 gates * UPW
#define THREADS 1024
#define NCPY   4         // replicated h copies (64 consumer WGs each)
#define SENT   0xFFFFFFFFu

__device__ __forceinline__ float wave_sum(float v) {
#pragma unroll
    for (int o = 32; o > 0; o >>= 1) v += __shfl_xor(v, o, 64);
    return v;
}

__device__ __forceinline__ float softplusf(float x) {
    return x > 0.f ? x + log1pf(expf(-x)) : log1pf(expf(x));
}
__device__ __forceinline__ float sigmoidf(float x) {
    return 1.f / (1.f + expf(-x));
}

// round-to-nearest-even fp32 -> bf16 (finite inputs; |h|<1 so never 0xFFFF)
__device__ __forceinline__ unsigned short f2bf(float f) {
    unsigned u = __float_as_uint(f);
    return (unsigned short)((u + 0x7FFFu + ((u >> 16) & 1u)) >> 16);
}

// EmbT[l*H + k] = Emb[k*LBLP1 + l]
__global__ void embT_kernel(const float* __restrict__ Emb, float* __restrict__ EmbT) {
    int l = blockIdx.x;
    for (int k = threadIdx.x; k < H; k += blockDim.x)
        EmbT[(size_t)l * H + k] = Emb[(size_t)k * LBLP1 + l];
}

// WEmb[row*33 + l] = dot(W[row,:], EmbT[l,:]) + d[row];  row = e*H + h
__global__ void wemb_kernel(const float* __restrict__ W, const float* __restrict__ EmbT,
                            const float* __restrict__ dbias, float* __restrict__ WEmb) {
    int row  = blockIdx.x;
    int wave = threadIdx.x >> 6;
    int lane = threadIdx.x & 63;
    __shared__ float wrow[H];
    for (int i = threadIdx.x; i < H; i += blockDim.x) wrow[i] = W[(size_t)row * H + i];
    __syncthreads();
    float db = dbias[row];
    for (int l = wave; l < LBLP1; l += 4) {
        const float* ec = EmbT + (size_t)l * H;
        float a = 0.f;
#pragma unroll
        for (int m = 0; m < 16; ++m) {
            int k = lane + (m << 6);
            a = fmaf(wrow[k], ec[k], a);
        }
        a = wave_sum(a);
        if (lane == 0) WEmb[(size_t)row * LBLP1 + l] = a + db;
    }
}

// Persistent dataflow scan, fan-out edition.
// 256 WGs x 1024 threads. Producers publish their 4-unit h slice as ONE packed
// 8B bf16 atomic store into NCPY replicated buffers; each group of 64 WGs polls
// only its own copy (64 readers/line instead of 256, bf16 halves the lines).
__global__ __launch_bounds__(THREADS)
void scan_kernel(const float* __restrict__ WEmb, const float* __restrict__ U,
                 const int* __restrict__ label_seq, const float* __restrict__ time_seq,
                 unsigned short* __restrict__ hcp,
                 float* __restrict__ all_h, float* __restrict__ all_o,
                 float* __restrict__ all_cb, float* __restrict__ all_cc,
                 float* __restrict__ all_dl) {
    const int tid  = threadIdx.x;
    const int wg   = blockIdx.x;
    const int wave = tid >> 6;
    const int lane = tid & 63;
    const int mycopy = wg >> 6;   // 64 WGs per copy

    extern __shared__ float smem[];
    float* Uld    = smem;                 // ROWS * H   (16B-aligned)
    float* h_sh   = Uld + ROWS * H;       // H          (16B-aligned)
    float* act_sh = h_sh + H;             // 32
    float* wes    = act_sh + 32;          // ROWS * LBLP1

    // One-time staging: 28 rows of U (coalesced over k) + WEmb slice.
    for (int idx = tid; idx < ROWS * H; idx += THREADS) {
        int r = idx >> 10, k = idx & (H - 1);
        int e = r >> 2, j = r & 3;
        Uld[idx] = U[((size_t)e * H + (wg * UPW + j)) * H + k];
    }
    for (int idx = tid; idx < ROWS * LBLP1; idx += THREADS) {
        int r = idx / LBLP1, l = idx - r * LBLP1;
        int e = r >> 2, j = r & 3;
        wes[idx] = WEmb[((size_t)e * H + (wg * UPW + j)) * LBLP1 + l];
    }
    __syncthreads();

    float c_t = 0.f, cbar = 0.f;
    const float4* h4 = (const float4*)h_sh;

    for (int t = 0; t < NSTEP; ++t) {
        const int   lab = label_seq[t];
        const float dt  = time_seq[t + 1] - time_seq[t];

        // gate biases for this wave's rows (waves 2..15 own rows 2*(w-2), +1)
        float gb0 = 0.f, gb1 = 0.f;
        int r0 = (wave - 2) << 1;
        if (wave >= 2) {
            gb0 = wes[r0 * LBLP1 + lab];
            gb1 = wes[(r0 + 1) * LBLP1 + lab];
        }

        // --- wave 0: acquire h_t from own bf16 copy; redistribute via LDS ---
        if (wave == 0) {
            unsigned v[8];
            if (t > 0) {
                const unsigned* src = (const unsigned*)
                    (hcp + ((size_t)mycopy * NSTEP + (t - 1)) * H);
                for (;;) {
                    bool ok = true;
#pragma unroll
                    for (int j = 0; j < 8; ++j)
                        v[j] = __hip_atomic_load(src + (j << 6) + lane,
                                                 __ATOMIC_RELAXED, __HIP_MEMORY_SCOPE_AGENT);
#pragma unroll
                    for (int j = 0; j < 8; ++j) ok &= (v[j] != SENT);
                    if (ok) break;
                }
            } else {
#pragma unroll
                for (int j = 0; j < 8; ++j) v[j] = 0;
            }
            // unpack 2 bf16 per dword; lane-interleaved float2 stores (2-way, free)
#pragma unroll
            for (int j = 0; j < 8; ++j) {
                float2 f2;
                if (t > 0) {
                    f2.x = __uint_as_float(v[j] << 16);
                    f2.y = __uint_as_float(v[j] & 0xFFFF0000u);
                } else f2 = make_float2(0.f, 0.f);
                ((float2*)h_sh)[(j << 6) + lane] = f2;
            }
        }
        __syncthreads();   // sync_a: h_sh ready

        // --- dots on waves 2..15 (2 rows each), activation fused ---
        if (wave >= 2) {
            float4 hr[4];
#pragma unroll
            for (int m = 0; m < 4; ++m) hr[m] = h4[(m << 6) + lane];
#pragma unroll
            for (int i = 0; i < 2; ++i) {
                int r = r0 + i;
                const float4* u4 = (const float4*)(Uld + (r << 10));
                float a = 0.f;
#pragma unroll
                for (int m = 0; m < 4; ++m) {
                    float4 u = u4[(m << 6) + lane];
                    a = fmaf(u.x, hr[m].x, a); a = fmaf(u.y, hr[m].y, a);
                    a = fmaf(u.z, hr[m].z, a); a = fmaf(u.w, hr[m].w, a);
                }
                a = wave_sum(a);
                float g = (i ? gb1 : gb0) + a;
                int e = r >> 2;
                float act;
                if (e == 2)      act = tanhf(g);
                else if (e == 6) act = softplusf(g);
                else             act = sigmoidf(g);
                if (lane == 0) act_sh[r] = act;
            }
        }
        __syncthreads();   // sync_b: act_sh ready

        // --- state update + packed bf16 publication (wave 0, lanes 0..3) ---
        if (tid < UPW) {
            float i_g = act_sh[tid],      f_g = act_sh[4 + tid];
            float z   = act_sh[8 + tid],  o   = act_sh[12 + tid];
            float i_b = act_sh[16 + tid], f_b = act_sh[20 + tid];
            float dl  = act_sh[24 + tid];
            float c   = fmaf(f_g, c_t, i_g * z);
            float cbn = fmaf(f_b, cbar, i_b * z);
            float ctn = cbn + (c - cbn) * expf(-dl * dt);
            float hn  = o * tanhf(ctn);
            c_t = ctn; cbar = cbn;
            size_t p = (size_t)t * H + wg * UPW + tid;
            all_h [p] = hn;
            all_o [p] = o;
            all_cb[p] = cbn;
            all_cc[p] = c;
            all_dl[p] = dl;
            // gather the 4 unit values into lane 0, pack, fan out to NCPY copies
            float h0 = __shfl(hn, 0), h1 = __shfl(hn, 1);
            float h2 = __shfl(hn, 2), h3 = __shfl(hn, 3);
            if (tid == 0) {
                unsigned long long pk =
                    (unsigned long long)f2bf(h0)
                  | ((unsigned long long)f2bf(h1) << 16)
                  | ((unsigned long long)f2bf(h2) << 32)
                  | ((unsigned long long)f2bf(h3) << 48);
                unsigned long long* base = (unsigned long long*)hcp;
#pragma unroll
                for (int cdst = 0; cdst < NCPY; ++cdst) {
                    __hip_atomic_store(base + ((size_t)cdst * NSTEP + t) * (H / 4) + wg,
                                       pk, __ATOMIC_RELAXED, __HIP_MEMORY_SCOPE_AGENT);
                }
            }
        }
        // no global barrier: step-(t+1) polls provide cross-WG ordering;
        // h_sh/act_sh rewrite hazards covered by sync_a/sync_b.
    }
}

__global__ void term1_kernel(const float* __restrict__ all_h, const int* __restrict__ label_seq,
                             const float* __restrict__ w, const float* __restrict__ log_s,
                             const int* __restrict__ ignore_first, float* __restrict__ acc) {
    int beg = (*ignore_first) ? 1 : 0;
    int j = blockIdx.x;
    if (j >= (NSTEP - 1 - beg)) return;
    if (label_seq[1 + beg + j] != TGT) return;
    const float* hrow = all_h + (size_t)(beg + j) * H;
    const float* w0 = w + (TGT - 1) * H;
    float part = 0.f;
    for (int i = threadIdx.x; i < H; i += blockDim.x) part += hrow[i] * w0[i];
    __shared__ float red[4];
    part = wave_sum(part);
    if ((threadIdx.x & 63) == 0) red[threadIdx.x >> 6] = part;
    __syncthreads();
    if (threadIdx.x == 0) {
        float tot = red[0] + red[1] + red[2] + red[3];
        float s0 = expf(log_s[TGT - 1]);
        float lam = s0 * softplusf(tot / s0) + 1e-9f;
        atomicAdd(acc, logf(lam));
    }
}

__global__ void term2_kernel(const float* __restrict__ all_o, const float* __restrict__ all_cb,
                             const float* __restrict__ all_cc, const float* __restrict__ all_dl,
                             const int* __restrict__ sim_idx, const float* __restrict__ sim_time,
                             const float* __restrict__ time_seq, const float* __restrict__ w,
                             const float* __restrict__ log_s, float* __restrict__ acc) {
    int i = blockIdx.x;
    int idx = sim_idx[i];
    float dtp = sim_time[i] - time_seq[idx];
    size_t base = (size_t)idx * H;
    const float* w0 = w + (TGT - 1) * H;
    float part = 0.f;
    for (int hh = threadIdx.x; hh < H; hh += blockDim.x) {
        float cb = all_cb[base + hh];
        float cc = all_cc[base + hh];
        float dl = all_dl[base + hh];
        float oo = all_o [base + hh];
        float cs = cb + (cc - cb) * expf(-dl * dtp);
        part += oo * tanhf(cs) * w0[hh];
    }
    __shared__ float red[4];
    part = wave_sum(part);
    if ((threadIdx.x & 63) == 0) red[threadIdx.x >> 6] = part;
    __syncthreads();
    if (threadIdx.x == 0) {
        float tot = red[0] + red[1] + red[2] + red[3];
        float s0 = expf(log_s[TGT - 1]);
        float lam = s0 * softplusf(tot / s0) + 1e-9f;
        atomicAdd(acc + 1, lam);
    }
}

__global__ void finish_kernel(const float* __restrict__ acc, const float* __restrict__ time_seq,
                              float* __restrict__ out) {
    float T = time_seq[NE - 1] - time_seq[0];
    out[0] = -(acc[0] - acc[1] * (T / (float)NS));
}

extern "C" void kernel_launch(void* const* d_in, const int* in_sizes, int n_in,
                              void* d_out, int out_size, void* d_ws, size_t ws_size,
                              hipStream_t stream) {
    const int*   label_seq    = (const int*)  d_in[0];
    const float* time_seq     = (const float*)d_in[1];
    const float* sim_time     = (const float*)d_in[2];
    const int*   sim_idx      = (const int*)  d_in[3];
    const int*   ignore_first = (const int*)  d_in[4];
    const float* Emb   = (const float*)d_in[5];
    const float* W     = (const float*)d_in[6];
    const float* U     = (const float*)d_in[7];
    const float* dbias = (const float*)d_in[8];
    const float* w     = (const float*)d_in[9];
    const float* log_s = (const float*)d_in[10];
    float* out = (float*)d_out;

    float* ws = (float*)d_ws;
    size_t off = 0;
    float* acc    = ws + off;  off += 32;                    // [0]=term1, [1]=term2-sum
    float* EmbT   = ws + off;  off += (size_t)LBLP1 * H;
    float* WEmb   = ws + off;  off += 7 * H * LBLP1;
    off = (off + 3) & ~(size_t)3;                            // 16B align
    float* all_h  = ws + off;  off += (size_t)NSTEP * H;
    float* all_o  = ws + off;  off += (size_t)NSTEP * H;
    float* all_cb = ws + off;  off += (size_t)NSTEP * H;
    float* all_cc = ws + off;  off += (size_t)NSTEP * H;
    float* all_dl = ws + off;  off += (size_t)NSTEP * H;
    unsigned short* hcp = (unsigned short*)(ws + off);       // NCPY*NSTEP*H bf16
    off += (size_t)NCPY * NSTEP * H / 2;                     // in float units

    hipMemsetAsync(acc, 0, 2 * sizeof(float), stream);
    // sentinel-fill the bf16 fan-out buffers (0xFFFF bf16 = NaN, never produced)
    hipMemsetAsync(hcp, 0xFF, (size_t)NCPY * NSTEP * H * sizeof(unsigned short), stream);

    hipLaunchKernelGGL(embT_kernel, dim3(LBLP1), dim3(256), 0, stream, Emb, EmbT);
    hipLaunchKernelGGL(wemb_kernel, dim3(7 * H), dim3(256), 0, stream,
                       W, EmbT, dbias, WEmb);

    unsigned int smem_bytes = (unsigned int)((ROWS * H + H + 32 + ROWS * LBLP1) * sizeof(float));
    hipFuncSetAttribute((const void*)scan_kernel, hipFuncAttributeMaxDynamicSharedMemorySize,
                        (int)smem_bytes);
    void* args[] = { (void*)&WEmb, (void*)&U, (void*)&label_seq, (void*)&time_seq,
                     (void*)&hcp, (void*)&all_h, (void*)&all_o, (void*)&all_cb,
                     (void*)&all_cc, (void*)&all_dl };
    // cooperative launch only for the co-residency guarantee (no grid.sync inside)
    hipLaunchCooperativeKernel((void*)scan_kernel, dim3(NWG), dim3(THREADS),
                               args, smem_bytes, stream);

    hipLaunchKernelGGL(term1_kernel, dim3(NSTEP - 1), dim3(256), 0, stream,
                       all_h, label_seq, w, log_s, ignore_first, acc);
    hipLaunchKernelGGL(term2_kernel, dim3(NS), dim3(256), 0, stream,
                       all_o, all_cb, all_cc, all_dl, sim_idx, sim_time, time_seq, w, log_s, acc);
    hipLaunchKernelGGL(finish_kernel, dim3(1), dim3(1), 0, stream, acc, time_seq, out);
}